// Round 7
// baseline (274.707 us; speedup 1.0000x reference)
//
#include <hip/hip_runtime.h>
#include <stdint.h>

#define ROWS 1024
#define IDIM 256
#define HDIM 1024

// ---------------- threefry2x32 (key = [0,42]) ----------------
__device__ __forceinline__ uint32_t rotl32(uint32_t x, int r){ return (x<<r)|(x>>(32-r)); }

__device__ __forceinline__ void threefry(uint32_t x0, uint32_t x1, uint32_t& o0, uint32_t& o1){
  const uint32_t k0 = 0u, k1 = 42u;
  const uint32_t k2 = 0x1BD11BDAu ^ k0 ^ k1;
  x0 += k0; x1 += k1;
#define TFR(r) { x0 += x1; x1 = rotl32(x1, r); x1 ^= x0; }
  TFR(13) TFR(15) TFR(26) TFR(6)  x0 += k1; x1 += k2 + 1u;
  TFR(17) TFR(29) TFR(16) TFR(24) x0 += k2; x1 += k0 + 2u;
  TFR(13) TFR(15) TFR(26) TFR(6)  x0 += k0; x1 += k1 + 3u;
  TFR(17) TFR(29) TFR(16) TFR(24) x0 += k1; x1 += k2 + 4u;
  TFR(13) TFR(15) TFR(26) TFR(6)  x0 += k2; x1 += k0 + 5u;
#undef TFR
  o0 = x0; o1 = x1;
}

// JAX >=0.4.36 default: threefry_partitionable=True.
// Per element i: counter = uint64(i) split as (hi=i>>32, lo=i), pair (hi, lo);
// 32-bit draw = o0 ^ o1. Then uniform: (bits>>9 | 0x3F800000) - 1.0 < p.
__global__ __launch_bounds__(256) void mask_kernel(const float* __restrict__ freq,
                                                   float* __restrict__ mkf)
{
  uint32_t i = blockIdx.x * 256u + threadIdx.x;   // [0, 2^20)
  uint32_t o0, o1;
  threefry(0u, i, o0, o1);                        // (hi, lo) = (0, i)
  uint32_t bits = o0 ^ o1;                        // partitionable 32-bit combine
  float u = __uint_as_float((bits >> 9) | 0x3F800000u) - 1.0f;
  mkf[i] = (u < freq[i & 1023u]) ? 1.0f : 0.0f;
}

// ---------------- argaug: per-row FIR correlation + argmax (fp64-exact ordering) ----------------
__global__ __launch_bounds__(256) void argaug_kernel(const float* __restrict__ x,
                                                     const float* __restrict__ y,
                                                     float* __restrict__ xaug)
{
  __shared__ float  xs[IDIM];
  __shared__ float  ys[IDIM];
  __shared__ float  kp[1024];
  __shared__ double rv[256];
  __shared__ int    rk[256];

  const int row  = blockIdx.x;
  const int tid  = threadIdx.x;
  const int wave = tid >> 6;
  const int lane = tid & 63;

  xs[tid] = x[row * IDIM + tid];
  ys[tid] = y[row * IDIM + tid];
  __syncthreads();

  double bestv = -1.0e300; int bestk = 0x3FFFFFFF;   // global best, lex-first (t,s)
  double t0v   = -1.0e300; int t0k   = 0x3FFFFFFF;   // theta0 argmax (fallback if global max <= 0)
  const int sbase = 192 * wave + 3 * lane;

  for (int t = 0; t < 9; ++t) {
    const int OL = 128 + 32 * t;            // out_len
    const double ratio = 256.0 / (double)OL;

    // zero-padded key in LDS: kp[255 .. 255+OL) = x_s, else 0
    for (int i = tid; i < 1024; i += 256) {
      float v = 0.0f;
      int j = i - 255;
      if (j >= 0 && j < OL) v = xs[(int)floor((double)j * ratio)];  // fp64 matches numpy
      kp[i] = v;
    }
    __syncthreads();

    double a0=0,a1=0,a2=0, n0=0,n1=0,n2=0;
    const int qlo = (wave == 0) ? 64 : 0;                 // all-zero region skip (wave-uniform)
    const int qhi = min(256, 255 + OL - 192 * wave);
    if (qhi > qlo) {
      int p = sbase + qlo;
      double c0 = (double)kp[p], c1 = (double)kp[p+1], c2 = (double)kp[p+2], c3;
      for (int q = qlo; q < qhi; q += 4) {
        float4 y4 = *(const float4*)&ys[q];
        double yd = (double)y4.x;
        a0 += yd*c0; n0 += c0*c0;
        a1 += yd*c1; n1 += c1*c1;
        a2 += yd*c2; n2 += c2*c2;
        c3 = (double)kp[p+3];
        yd = (double)y4.y;
        a0 += yd*c1; n0 += c1*c1;
        a1 += yd*c2; n1 += c2*c2;
        a2 += yd*c3; n2 += c3*c3;
        c0 = (double)kp[p+4];
        yd = (double)y4.z;
        a0 += yd*c2; n0 += c2*c2;
        a1 += yd*c3; n1 += c3*c3;
        a2 += yd*c0; n2 += c0*c0;
        c1 = (double)kp[p+5];
        yd = (double)y4.w;
        a0 += yd*c3; n0 += c3*c3;
        a1 += yd*c0; n1 += c0*c0;
        a2 += yd*c1; n2 += c1*c1;
        c2 = (double)kp[p+6];
        p += 4;
      }
    }

    const int nsh = OL + 255;
#define UPD(S, A, N) { int s = (S); if (s < nsh && (N) > 0.0) { double v = (A) / sqrt((N)); \
      if (v > bestv) { bestv = v; bestk = (t << 10) | s; } \
      if (t == 0 && v > t0v) { t0v = v; t0k = s; } } }
    UPD(sbase,     a0, n0)
    UPD(sbase + 1, a1, n1)
    UPD(sbase + 2, a2, n2)
#undef UPD
    __syncthreads();   // before next theta rebuilds kp
  }

  // block argmax #1: global, tie-break lexicographically smallest (theta, s)
  rv[tid] = bestv; rk[tid] = bestk;
  __syncthreads();
  for (int off = 128; off > 0; off >>= 1) {
    if (tid < off) {
      double v2 = rv[tid+off]; int k2 = rk[tid+off];
      if (v2 > rv[tid] || (v2 == rv[tid] && k2 < rk[tid])) { rv[tid] = v2; rk[tid] = k2; }
    }
    __syncthreads();
  }
  const double gbest = rv[0];
  const int    gk    = rk[0];
  __syncthreads();

  // block argmax #2: theta0 only (reference keeps theta0 window when global max <= 0)
  rv[tid] = t0v; rk[tid] = t0k;
  __syncthreads();
  for (int off = 128; off > 0; off >>= 1) {
    if (tid < off) {
      double v2 = rv[tid+off]; int k2 = rk[tid+off];
      if (v2 > rv[tid] || (v2 == rv[tid] && k2 < rk[tid])) { rv[tid] = v2; rk[tid] = k2; }
    }
    __syncthreads();
  }
  const int wk = (gbest > 0.0) ? gk : rk[0];   // rk[0] here = theta0 argmax s (t=0)

  const int tb = wk >> 10, sb = wk & 1023;
  const int OLb = 128 + 32 * tb;
  const double ratiob = 256.0 / (double)OLb;
  int j = sb + tid - 255;
  float v = 0.0f;
  if (j >= 0 && j < OLb) v = xs[(int)floor((double)j * ratiob)];
  xaug[row * IDIM + tid] = v;
}

// ---------------- GEMM1: h = (xaug @ W1 + b1) * mk  (1024x256 @ 256x1024) ----------------
__global__ __launch_bounds__(256) void gemm1_kernel(const float* __restrict__ A,
                                                    const float* __restrict__ W1,
                                                    const float* __restrict__ b1,
                                                    const float* __restrict__ mkf,
                                                    float* __restrict__ h)
{
  __shared__ float As[32][68];
  __shared__ float Bs[32][68];
  const int tid = threadIdx.x;
  const int m0 = blockIdx.x * 64;
  const int n0 = blockIdx.y * 64;
  const int tx = tid & 15, ty = tid >> 4;
  float acc[4][4] = {};

  for (int kt = 0; kt < 256; kt += 32) {
#pragma unroll
    for (int jj = 0; jj < 8; ++jj) {
      int f = tid + 256*jj;
      As[f & 31][f >> 5] = A[(m0 + (f >> 5)) * 256 + kt + (f & 31)];
    }
#pragma unroll
    for (int jj = 0; jj < 8; ++jj) {
      int f = tid + 256*jj;
      Bs[f >> 6][f & 63] = W1[(kt + (f >> 6)) * 1024 + n0 + (f & 63)];
    }
    __syncthreads();
#pragma unroll
    for (int kk = 0; kk < 32; ++kk) {
      float4 a4 = *(const float4*)&As[kk][4*ty];
      float4 b4 = *(const float4*)&Bs[kk][4*tx];
      acc[0][0] += a4.x*b4.x; acc[0][1] += a4.x*b4.y; acc[0][2] += a4.x*b4.z; acc[0][3] += a4.x*b4.w;
      acc[1][0] += a4.y*b4.x; acc[1][1] += a4.y*b4.y; acc[1][2] += a4.y*b4.z; acc[1][3] += a4.y*b4.w;
      acc[2][0] += a4.z*b4.x; acc[2][1] += a4.z*b4.y; acc[2][2] += a4.z*b4.z; acc[2][3] += a4.z*b4.w;
      acc[3][0] += a4.w*b4.x; acc[3][1] += a4.w*b4.y; acc[3][2] += a4.w*b4.z; acc[3][3] += a4.w*b4.w;
    }
    __syncthreads();
  }

  float4 bias = *(const float4*)&b1[n0 + 4*tx];
#pragma unroll
  for (int r = 0; r < 4; ++r) {
    int m = m0 + 4*ty + r;
    float4 mk4 = *(const float4*)&mkf[m * 1024 + n0 + 4*tx];
    float4 o;
    o.x = (acc[r][0] + bias.x) * mk4.x;
    o.y = (acc[r][1] + bias.y) * mk4.y;
    o.z = (acc[r][2] + bias.z) * mk4.z;
    o.w = (acc[r][3] + bias.w) * mk4.w;
    *(float4*)&h[m * 1024 + n0 + 4*tx] = o;
  }
}

// ---------------- GEMM2 (split-K=4): out_acc += h @ W2  (1024x1024 @ 1024x256) ----------------
__global__ __launch_bounds__(256) void gemm2_kernel(const float* __restrict__ h,
                                                    const float* __restrict__ W2,
                                                    float* __restrict__ out_acc)
{
  __shared__ float As[32][68];
  __shared__ float Bs[32][68];
  const int tid = threadIdx.x;
  const int m0 = blockIdx.x * 64;        // 16
  const int n0 = blockIdx.y * 64;        // 4
  const int kz = blockIdx.z * 256;       // 4
  const int tx = tid & 15, ty = tid >> 4;
  float acc[4][4] = {};

  for (int kt = 0; kt < 256; kt += 32) {
#pragma unroll
    for (int jj = 0; jj < 8; ++jj) {
      int f = tid + 256*jj;
      As[f & 31][f >> 5] = h[(m0 + (f >> 5)) * 1024 + kz + kt + (f & 31)];
    }
#pragma unroll
    for (int jj = 0; jj < 8; ++jj) {
      int f = tid + 256*jj;
      Bs[f >> 6][f & 63] = W2[(kz + kt + (f >> 6)) * 256 + n0 + (f & 63)];
    }
    __syncthreads();
#pragma unroll
    for (int kk = 0; kk < 32; ++kk) {
      float4 a4 = *(const float4*)&As[kk][4*ty];
      float4 b4 = *(const float4*)&Bs[kk][4*tx];
      acc[0][0] += a4.x*b4.x; acc[0][1] += a4.x*b4.y; acc[0][2] += a4.x*b4.z; acc[0][3] += a4.x*b4.w;
      acc[1][0] += a4.y*b4.x; acc[1][1] += a4.y*b4.y; acc[1][2] += a4.y*b4.z; acc[1][3] += a4.y*b4.w;
      acc[2][0] += a4.z*b4.x; acc[2][1] += a4.z*b4.y; acc[2][2] += a4.z*b4.z; acc[2][3] += a4.z*b4.w;
      acc[3][0] += a4.w*b4.x; acc[3][1] += a4.w*b4.y; acc[3][2] += a4.w*b4.z; acc[3][3] += a4.w*b4.w;
    }
    __syncthreads();
  }

#pragma unroll
  for (int r = 0; r < 4; ++r)
#pragma unroll
    for (int c = 0; c < 4; ++c)
      unsafeAtomicAdd(&out_acc[(m0 + 4*ty + r) * 256 + n0 + 4*tx + c], acc[r][c]);
}

// ---------------- finalize: out = acc + b2 + xaug; loss partials ----------------
__global__ __launch_bounds__(256) void finalize_kernel(const float* __restrict__ out_acc,
                                                       const float* __restrict__ b2,
                                                       const float* __restrict__ xaug,
                                                       const float* __restrict__ yref,
                                                       float* __restrict__ d_out,
                                                       double* __restrict__ loss_acc,
                                                       unsigned int* __restrict__ cnt_acc)
{
  __shared__ double sred[4];
  __shared__ unsigned int cred[4];
  int i = blockIdx.x * 256 + threadIdx.x;
  int n = i & 255;
  float v = out_acc[i] + b2[n] + xaug[i];
  d_out[1 + i] = v;
  float yv = yref[i];
  bool valid = (yv != 0.0f);
  float df = v - yv;
  double lsd = valid ? (double)df * (double)df : 0.0;
#pragma unroll
  for (int off = 32; off > 0; off >>= 1) lsd += __shfl_down(lsd, off, 64);
  unsigned long long bal = __ballot(valid);
  int wv = threadIdx.x >> 6, ln = threadIdx.x & 63;
  if (ln == 0) { sred[wv] = lsd; cred[wv] = (unsigned int)__popcll(bal); }
  __syncthreads();
  if (threadIdx.x == 0) {
    double s = sred[0] + sred[1] + sred[2] + sred[3];
    unsigned int c = cred[0] + cred[1] + cred[2] + cred[3];
    atomicAdd(loss_acc, s);
    atomicAdd(cnt_acc, c);
  }
}

__global__ void loss_kernel(const double* __restrict__ loss_acc,
                            const unsigned int* __restrict__ cnt_acc,
                            float* __restrict__ d_out)
{
  d_out[0] = (float)(loss_acc[0] / (double)cnt_acc[0]);
}

// ---------------- launch ----------------
extern "C" void kernel_launch(void* const* d_in, const int* in_sizes, int n_in,
                              void* d_out, int out_size, void* d_ws, size_t ws_size,
                              hipStream_t stream) {
  const float* x    = (const float*)d_in[0];
  const float* y    = (const float*)d_in[1];
  const float* W1   = (const float*)d_in[2];
  const float* b1   = (const float*)d_in[3];
  const float* W2   = (const float*)d_in[4];
  const float* b2   = (const float*)d_in[5];
  const float* freq = (const float*)d_in[6];
  float* out = (float*)d_out;

  char* ws = (char*)d_ws;
  float*  xaug = (float*)(ws);                        // 1 MB
  float*  h    = (float*)(ws + (1u<<20));             // 4 MB
  float*  mkf  = (float*)(ws + 5u*(1u<<20));          // 4 MB
  float*  oacc = (float*)(ws + 9u*(1u<<20));          // 1 MB
  double* lacc = (double*)(ws + 10u*(1u<<20));        // 8 B
  unsigned int* cacc = (unsigned int*)(ws + 10u*(1u<<20) + 8u);

  hipMemsetAsync(ws + 9u*(1u<<20), 0, (1u<<20) + 16u, stream);

  mask_kernel  <<<4096, 256, 0, stream>>>(freq, mkf);
  argaug_kernel<<<1024, 256, 0, stream>>>(x, y, xaug);
  gemm1_kernel <<<dim3(16,16),  256, 0, stream>>>(xaug, W1, b1, mkf, h);
  gemm2_kernel <<<dim3(16,4,4), 256, 0, stream>>>(h, W2, oacc);
  finalize_kernel<<<1024, 256, 0, stream>>>(oacc, b2, xaug, y, out, lacc, cacc);
  loss_kernel  <<<1, 1, 0, stream>>>(lacc, cacc, out);
}